// Round 1
// baseline (96.740 us; speedup 1.0000x reference)
//
#include <hip/hip_runtime.h>

// PointGenerator: out[i] = A[c] @ [x*d, y*d, d, 1], A[c] = E(c) @ n2r @ K(c)^-1 folded.
// Inputs (setup_inputs order):
//   0: point_indices (N,3) int32   [c,y,x]
//   1: depth         (N,1) f32
//   2: image_coords  (H,W,2) f32   -- provably unused: image_coords[y,x]-0.5 == (y,x) exactly
//   3: camera_to_worlds (C,3,4) f32
//   4: intrinsics    (C,3,3) f32
// Output: (N,4) f32, last component == 1.

#define MAXCAM 256  // problem has 200 cameras; LDS table sized with headroom

__global__ __launch_bounds__(256) void pointgen_kernel(
    const int*   __restrict__ pi,     // (N,3)
    const float* __restrict__ depth,  // (N,)
    const float* __restrict__ c2w,    // (C,3,4)
    const float* __restrict__ intr,   // (C,3,3)
    float4*      __restrict__ out,    // (N,) float4
    int N, int ncam)
{
    // Per-block camera table: A[c] as 3 float4 rows.
    // col0 = R_col0/f, col1 = -R_col1/f, col2 = (cy*R_col1 - cx*R_col0)/f - R_col2, col3 = t
    __shared__ float4 camA[MAXCAM * 3];

    for (int cam = (int)threadIdx.x; cam < ncam; cam += (int)blockDim.x) {
        const float* e = c2w  + cam * 12;  // rows of [R|t]
        const float* k = intr + cam * 9;
        float f  = k[0];
        float cx = k[2];
        float cy = k[5];
        float invf = 1.0f / f;
        #pragma unroll
        for (int r = 0; r < 3; ++r) {
            float R0 = e[r * 4 + 0];
            float R1 = e[r * 4 + 1];
            float R2 = e[r * 4 + 2];
            float tr = e[r * 4 + 3];
            float4 a;
            a.x = R0 * invf;
            a.y = -R1 * invf;
            a.z = (cy * R1 - cx * R0) * invf - R2;
            a.w = tr;
            camA[cam * 3 + r] = a;
        }
    }
    __syncthreads();

    int stride = (int)(gridDim.x * blockDim.x);
    for (int i = (int)(blockIdx.x * blockDim.x + threadIdx.x); i < N; i += stride) {
        int c = pi[3 * i + 0];
        int y = pi[3 * i + 1];
        int x = pi[3 * i + 2];
        float d = depth[i];
        float xd = (float)x * d;
        float yd = (float)y * d;
        float4 r0 = camA[c * 3 + 0];
        float4 r1 = camA[c * 3 + 1];
        float4 r2 = camA[c * 3 + 2];
        float4 o;
        o.x = fmaf(r0.x, xd, fmaf(r0.y, yd, fmaf(r0.z, d, r0.w)));
        o.y = fmaf(r1.x, xd, fmaf(r1.y, yd, fmaf(r1.z, d, r1.w)));
        o.z = fmaf(r2.x, xd, fmaf(r2.y, yd, fmaf(r2.z, d, r2.w)));
        o.w = 1.0f;
        out[i] = o;
    }
}

extern "C" void kernel_launch(void* const* d_in, const int* in_sizes, int n_in,
                              void* d_out, int out_size, void* d_ws, size_t ws_size,
                              hipStream_t stream) {
    const int*   pi    = (const int*)d_in[0];
    const float* depth = (const float*)d_in[1];
    // d_in[2] (image_coords) intentionally unused — identity after the -0.5.
    const float* c2w   = (const float*)d_in[3];
    const float* intr  = (const float*)d_in[4];
    float4* out = (float4*)d_out;

    int N    = in_sizes[1];          // depth has N elements
    int ncam = in_sizes[3] / 12;     // (C,3,4)
    if (ncam > MAXCAM) ncam = MAXCAM;

    int block = 256;
    int grid  = 1024;                // 4 blocks/CU, 16 waves/CU; grid-stride covers N
    int max_grid = (N + block - 1) / block;
    if (grid > max_grid) grid = max_grid;

    pointgen_kernel<<<grid, block, 0, stream>>>(pi, depth, c2w, intr, out, N, ncam);
}